// Round 13
// baseline (19.905 us; speedup 1.0000x reference)
//
#include <hip/hip_runtime.h>
#include <math.h>

#define NT 256
#define NB 1024
#define AST 104        // A row stride (halfwords) = 52 dwords; col a <-> image col w0c+a
#define BST 102        // B row stride (halfwords) = 51 dwords; B col = A col (2..101 used)

// f32 -> bf16 bits, round-to-nearest-even (inputs finite, >= 0)
__device__ __forceinline__ unsigned short f2b(float f) {
    unsigned int u = __float_as_uint(f);
    u += 0x7FFFu + ((u >> 16) & 1u);
    return (unsigned short)(u >> 16);
}

// packed unsigned 16-bit min (elementwise on two bf16-bit lanes; valid: values >= 0)
__device__ __forceinline__ unsigned pkmin(unsigned a, unsigned b) {
    unsigned d;
    asm("v_pk_min_u16 %0, %1, %2" : "=v"(d) : "v"(a), "v"(b));
    return d;
}

// Vertical sliding-35 min, packed col-pair p (dword), out rows 8qc..8qc+7
__device__ __forceinline__ void vtask(const unsigned* __restrict__ Au,
                                      unsigned* __restrict__ Bu, int qc, int p) {
    const int base = (8 * qc) * 52 + p;
    unsigned w[42];
    #pragma unroll
    for (int i = 0; i < 42; ++i) w[i] = Au[base + 52 * i];
    __builtin_amdgcn_sched_barrier(0);           // keep the 42 reads batched
    #pragma unroll
    for (int i = 0; i <= 40; ++i) w[i] = pkmin(w[i], w[i + 1]);
    #pragma unroll
    for (int i = 0; i <= 38; ++i) w[i] = pkmin(w[i], w[i + 2]);
    #pragma unroll
    for (int i = 0; i <= 34; ++i) w[i] = pkmin(w[i], w[i + 4]);
    #pragma unroll
    for (int i = 0; i <= 26; ++i) w[i] = pkmin(w[i], w[i + 8]);
    #pragma unroll
    for (int i = 0; i <= 10; ++i) w[i] = pkmin(w[i], w[i + 16]);
    #pragma unroll
    for (int k = 0; k < 8; ++k)                  // out row 8qc+k = min rows ..+34
        Bu[(8 * qc + k) * 51 + p] = pkmin(w[k], w[k + 3]);
}

// Horizontal sliding-35 min + partial sum for out row r, 8-col chunk c
__device__ __forceinline__ float htask(const unsigned* __restrict__ Bu, int r, int c) {
    const int base = r * 51 + 4 * c + 1;         // dword idx of B halfword col 8c+2
    int h[44];
    #pragma unroll
    for (int i = 0; i < 22; ++i) {               // banks 2-way across wave (free)
        const unsigned u = Bu[base + i];
        h[2 * i]     = (int)(u & 0xFFFFu);
        h[2 * i + 1] = (int)(u >> 16);
    }
    __builtin_amdgcn_sched_barrier(0);           // keep the 22 reads batched
    #pragma unroll
    for (int i = 0; i <= 42; ++i) h[i] = min(h[i], h[i + 1]);
    #pragma unroll
    for (int i = 0; i <= 40; ++i) h[i] = min(h[i], h[i + 2]);
    #pragma unroll
    for (int i = 0; i <= 36; ++i) h[i] = min(h[i], h[i + 4]);
    #pragma unroll
    for (int i = 0; i <= 28; ++i) h[i] = min(h[i], h[i + 8]);
    #pragma unroll
    for (int i = 0; i <= 12; ++i) h[i] = min(h[i], h[i + 16]);
    float s = 0.0f;
    #pragma unroll
    for (int k = 0; k < 8; ++k) {
        const int mb = min(h[k + 1], h[k + 4]);  // 35-min bits, out col 8c+k
        s += 1.0f - __uint_as_float((unsigned)mb << 16);   // dc >= 0
    }
    return s;
}

__global__ __launch_bounds__(NT, 4)
void dark_main(const float* __restrict__ x, float* __restrict__ part) {
    __shared__ unsigned short A[98 * AST];   // 20384 B: bf16 bits of m=min_c(x); pad=1.0
    __shared__ unsigned short B[64 * BST];   // 13056 B: vertical 35-min bits
    __shared__ float red[4];                 // ~33.5 KB total -> 4 blocks/CU

    const int tid = threadIdx.x;
    const int bid = blockIdx.x;
    // XCD swizzle: XCD k -> 128 consecutive tiles = images 2k, 2k+1
    const int swz = (bid & 7) * 128 + (bid >> 3);
    const int b   = swz >> 6;                // 64 tiles per image (8x8 of 64x64)
    const int ty  = (swz >> 3) & 7;
    const int tx  = swz & 7;
    const int h0  = ty * 64 - 17;            // region row k <-> image row h0+k, k in [0,98)
    const int w0c = tx * 64 - 20;            // A col a <-> image col w0c+a (f4-aligned)
    const float* xb = x + (size_t)b * 786432u;

    // ---- Phase 0: staged software-pipelined loads (4/4/2 slots; 24 loads peak) ----
    // w0c % 4 == 0 and width 512 % 4 == 0 => every f4-group is fully in/out of bounds.
    // Issue slots 0-3, issue 4-7, process 0-3 (overlaps 4-7's flight), issue 8-9,
    // process 4-7, process 8-9. Peak live: ~96 data VGPR + addressing < 128 cap.
    {
        float4 ra[4][3], rb[4][3], rc[2][3];
        #define P0_ADDR(s)                                                    \
            const int t   = tid + 256 * (s);                                  \
            const int k   = t / 26, g = t - 26 * k;                           \
            const int gh  = h0 + k;                                           \
            const int ghc = gh < 0 ? 0 : (gh > 511 ? 511 : gh);               \
            const int gw  = w0c + 4 * g;                                      \
            const int gwc = gw < 0 ? 0 : (gw > 508 ? 508 : gw);               \
            const float* p = xb + (size_t)ghc * 512u + gwc;
        #define P0_ISSUE(dst, s)                                              \
            { P0_ADDR(s)                                                      \
              dst[0] = *(const float4*)p;                                     \
              dst[1] = *(const float4*)(p + 262144);                          \
              dst[2] = *(const float4*)(p + 524288); }
        #define P0_PROC(src, s)                                               \
            { P0_ADDR(s) (void)p; (void)gwc;                                  \
              if (t < 98 * 26) {                                              \
                const bool ok = ((unsigned)gh < 512u) && ((unsigned)gw < 512u);\
                float m0 = fminf(src[0].x, fminf(src[1].x, src[2].x));        \
                float m1 = fminf(src[0].y, fminf(src[1].y, src[2].y));        \
                float m2 = fminf(src[0].z, fminf(src[1].z, src[2].z));        \
                float m3 = fminf(src[0].w, fminf(src[1].w, src[2].w));        \
                if (!ok) { m0 = m1 = m2 = m3 = 1.0f; }                        \
                uint2 pk;                                                     \
                pk.x = (unsigned)f2b(m0) | ((unsigned)f2b(m1) << 16);         \
                pk.y = (unsigned)f2b(m2) | ((unsigned)f2b(m3) << 16);         \
                *(uint2*)&A[k * AST + 4 * g] = pk;                            \
              } }

        #pragma unroll
        for (int s = 0; s < 4; ++s) P0_ISSUE(ra[s], s)
        #pragma unroll
        for (int s = 0; s < 4; ++s) P0_ISSUE(rb[s], 4 + s)
        __builtin_amdgcn_sched_barrier(0);       // 24 loads in flight
        #pragma unroll
        for (int s = 0; s < 4; ++s) P0_PROC(ra[s], s)
        #pragma unroll
        for (int s = 0; s < 2; ++s) P0_ISSUE(rc[s], 8 + s)
        __builtin_amdgcn_sched_barrier(0);       // rb+rc (18) still in flight
        #pragma unroll
        for (int s = 0; s < 4; ++s) P0_PROC(rb[s], 4 + s)
        #pragma unroll
        for (int s = 0; s < 2; ++s) P0_PROC(rc[s], 8 + s)
        #undef P0_ISSUE
        #undef P0_PROC
        #undef P0_ADDR
    }
    __syncthreads();

    // ---- Phase V: packed col-pair sliding-35 min; 8 chunks over 2 passes ----
    // Wave w, lanes 0..49 own A dword-col p = lane+1 (A halfword cols 2..101).
    {
        const int wv   = tid >> 6;
        const int lane = tid & 63;
        const unsigned* Au = (const unsigned*)A;   // row stride 52 dwords
        unsigned* Bu = (unsigned*)B;               // row stride 51 dwords
        const int p = lane + 1;
        if (lane < 50) vtask(Au, Bu, wv, p);       // out rows 0..31
        if (lane < 50) vtask(Au, Bu, wv + 4, p);   // out rows 32..63
    }
    __syncthreads();

    // ---- Phase H: 512 tasks, 2 per thread (100% lanes) ----
    float s = 0.0f;
    {
        const unsigned* Bu = (const unsigned*)B;
        s += htask(Bu, tid >> 3, tid & 7);              // rows 0..31
        s += htask(Bu, 32 + (tid >> 3), tid & 7);       // rows 32..63
    }

    // ---- block reduction (deterministic) ----
    #pragma unroll
    for (int off = 32; off; off >>= 1) s += __shfl_down(s, off);
    if ((tid & 63) == 0) red[tid >> 6] = s;
    __syncthreads();
    if (tid == 0) part[bid] = red[0] + red[1] + red[2] + red[3];
}

__global__ void dark_reduce(const float* __restrict__ part, float* __restrict__ out) {
    const int tid = threadIdx.x;
    float s = 0.0f;
    #pragma unroll
    for (int i = 0; i < 4; ++i) s += part[tid + 256 * i];   // fixed order
    #pragma unroll
    for (int off = 32; off; off >>= 1) s += __shfl_down(s, off);
    __shared__ float w[4];
    if ((tid & 63) == 0) w[tid >> 6] = s;
    __syncthreads();
    if (tid == 0)
        out[0] = -(w[0] + w[1] + w[2] + w[3]) * (1.0f / 4194304.0f);  // -mean
}

extern "C" void kernel_launch(void* const* d_in, const int* in_sizes, int n_in,
                              void* d_out, int out_size, void* d_ws, size_t ws_size,
                              hipStream_t stream) {
    const float* x = (const float*)d_in[0];
    float* out  = (float*)d_out;
    float* part = (float*)d_ws;                  // 1024 floats, fully rewritten each call

    hipLaunchKernelGGL(dark_main,   dim3(NB), dim3(NT), 0, stream, x, part);
    hipLaunchKernelGGL(dark_reduce, dim3(1),  dim3(NT), 0, stream, part, out);
}